// Round 1
// baseline (522.877 us; speedup 1.0000x reference)
//
#include <hip/hip_runtime.h>

typedef float f32x4 __attribute__((ext_vector_type(4)));
typedef unsigned short us8 __attribute__((ext_vector_type(8)));

#define DEVINL __device__ __forceinline__

DEVINL unsigned short f2bf(float f) {
  unsigned u = __builtin_bit_cast(unsigned, f);
  u += 0x7fffu + ((u >> 16) & 1u);
  return (unsigned short)(u >> 16);
}
DEVINL float bf2f(unsigned short b) { return __builtin_bit_cast(float, ((unsigned)b) << 16); }
DEVINL us8 ld8(const unsigned short* p) { return *reinterpret_cast<const us8*>(p); }
DEVINL void mfma_bf16(f32x4& acc, us8 a, us8 b) {
  asm("v_mfma_f32_16x16x32_bf16 %0, %1, %2, %0" : "+v"(acc) : "v"(a), "v"(b));
}

// ---------------- elementwise convert fp32 -> bf16 (x4 vectorized) ----------------
__global__ void k_cvt(const float* __restrict__ in, unsigned short* __restrict__ out, int n4) {
  int i = blockIdx.x * 256 + threadIdx.x;
  if (i >= n4) return;
  float4 v = reinterpret_cast<const float4*>(in)[i];
  unsigned lo = (unsigned)f2bf(v.x) | ((unsigned)f2bf(v.y) << 16);
  unsigned hi = (unsigned)f2bf(v.z) | ((unsigned)f2bf(v.w) << 16);
  reinterpret_cast<uint2*>(out)[i] = make_uint2(lo, hi);
}

// ---------------- RoPE freq tables (replicates reference fp32 semantics) ----------------
__global__ void k_freqs(float* __restrict__ cosT, float* __restrict__ sinT) {
  int idx = blockIdx.x * 256 + threadIdx.x;
  if (idx >= 2048 * 1024) return;
  int s = idx >> 10, i = idx & 1023;
  float e = (float)(2 * i);
  float pw = powf(10000.0f, e);          // overflows to inf for e>=10 -> tn = 0, matches fp32 ref
  float tn = 1.0f / (pw / 2048.0f);
  float ang = (float)s * tn;
  cosT[idx] = cosf(ang);
  sinT[idx] = sinf(ang);
}

// ---------------- GEMM: C[M,N] = A[M,K] * B[N,K]^T + bias, bf16 in, bf16/f32 out ----------------
template <bool OUTF32>
__global__ __launch_bounds__(256) void k_gemm_bt(const unsigned short* __restrict__ A,
                                                 const unsigned short* __restrict__ B,
                                                 const float* __restrict__ bias,
                                                 void* __restrict__ Cout, int M, int N, int K) {
  __shared__ unsigned short As[128 * 32];
  __shared__ unsigned short Bs[128 * 32];
  const int tid = threadIdx.x, lane = tid & 63, w = tid >> 6;
  const int g = lane >> 4, l16 = lane & 15;
  const int bn = blockIdx.x, bm = blockIdx.y;
  const int wm = w >> 1, wn = w & 1;
  f32x4 acc[4][4] = {};
  const unsigned short* Arow = A + (size_t)bm * 128 * K;
  const unsigned short* Brow = B + (size_t)bn * 128 * K;
  for (int kt = 0; kt < K; kt += 32) {
    __syncthreads();
#pragma unroll
    for (int j = 0; j < 2; ++j) {
      int c = (j * 4 + w) * 64 + lane;  // 0..511 16B chunks
      int row = c >> 2, c4 = c & 3;
      *reinterpret_cast<us8*>(&As[c * 8]) =
          *reinterpret_cast<const us8*>(&Arow[(size_t)row * K + kt + c4 * 8]);
      *reinterpret_cast<us8*>(&Bs[c * 8]) =
          *reinterpret_cast<const us8*>(&Brow[(size_t)row * K + kt + c4 * 8]);
    }
    __syncthreads();
    us8 af[4], bfg[4];
#pragma unroll
    for (int mm = 0; mm < 4; ++mm) af[mm] = ld8(&As[(wm * 64 + mm * 16 + l16) * 32 + g * 8]);
#pragma unroll
    for (int nn = 0; nn < 4; ++nn) bfg[nn] = ld8(&Bs[(wn * 64 + nn * 16 + l16) * 32 + g * 8]);
#pragma unroll
    for (int mm = 0; mm < 4; ++mm)
#pragma unroll
      for (int nn = 0; nn < 4; ++nn) mfma_bf16(acc[mm][nn], af[mm], bfg[nn]);
  }
#pragma unroll
  for (int nn = 0; nn < 4; ++nn) {
    int col = bn * 128 + wn * 64 + nn * 16 + l16;
    float bv = bias[col];
#pragma unroll
    for (int mm = 0; mm < 4; ++mm) {
      int row0 = bm * 128 + wm * 64 + mm * 16 + g * 4;
#pragma unroll
      for (int r = 0; r < 4; ++r) {
        float vv = acc[mm][nn][r] + bv;
        if (OUTF32)
          reinterpret_cast<float*>(Cout)[(size_t)(row0 + r) * N + col] = vv;
        else
          reinterpret_cast<unsigned short*>(Cout)[(size_t)(row0 + r) * N + col] = f2bf(vv);
      }
    }
  }
}

// ---------------- q/k = ct + rope(rl) ----------------
__global__ void k_rope_combine(const unsigned short* __restrict__ ct,
                               const unsigned short* __restrict__ rl,
                               const float* __restrict__ cosT, const float* __restrict__ sinT,
                               unsigned short* __restrict__ outp) {
  int pidx = blockIdx.x * 256 + threadIdx.x;  // pair index
  if (pidx >= 4096 * 1024) return;
  int row = pidx >> 10, i = pidx & 1023;
  int s = row & 2047;
  float c = cosT[s * 1024 + i], sn = sinT[s * 1024 + i];
  int base = row * 2048 + i * 2;
  float xe = bf2f(rl[base]), xo = bf2f(rl[base + 1]);
  float re = xe * c - xo * sn;
  float im = xe * sn + xo * c;
  float q0 = bf2f(ct[base]) + re;
  float q1 = bf2f(ct[base + 1]) + im;
  unsigned pack = (unsigned)f2bf(q0) | ((unsigned)f2bf(q1) << 16);
  *reinterpret_cast<unsigned*>(&outp[base]) = pack;
}

// ---------------- V transpose: v[4096][2048] -> vt[b][h][d][s] ----------------
__global__ __launch_bounds__(256) void k_transpose_v(const unsigned short* __restrict__ v,
                                                     unsigned short* __restrict__ vt) {
  __shared__ unsigned short t[32][33];
  int tx = threadIdx.x & 31, ty = threadIdx.x >> 5;
  int r0 = blockIdx.y * 32, c0 = blockIdx.x * 32;
#pragma unroll
  for (int jj = 0; jj < 4; ++jj)
    t[ty * 4 + jj][tx] = v[(size_t)(r0 + ty * 4 + jj) * 2048 + c0 + tx];
  __syncthreads();
  int b = r0 >> 11;
#pragma unroll
  for (int jj = 0; jj < 4; ++jj) {
    int colc = c0 + ty * 4 + jj;
    size_t orow = (size_t)(b * 16 + (colc >> 7)) * 128 + (colc & 127);
    vt[orow * 2048 + (r0 & 2047) + tx] = t[tx][ty * 4 + jj];
  }
}

// ---------------- flash attention: 4 waves x 16 q-rows, KV tile 64, swapped-QK ----------------
__global__ __launch_bounds__(256) void k_attn(const unsigned short* __restrict__ Q,
                                              const unsigned short* __restrict__ Kg,
                                              const unsigned short* __restrict__ VT,
                                              unsigned short* __restrict__ Aout) {
  __shared__ unsigned short Ks[64 * 128];
  __shared__ unsigned short VTs[128 * 64];
  __shared__ unsigned short Ps[4][1024];
  const int tid = threadIdx.x, lane = tid & 63, w = tid >> 6;
  const int g = lane >> 4, l16 = lane & 15;
  const int qt = blockIdx.x, h = blockIdx.y, b = blockIdx.z;
  const float SCALE = 0.08838834764831845f;  // 1/sqrt(128)
  const size_t qrow = (size_t)b * 2048 + qt * 64 + w * 16 + l16;
  us8 qf[4];
#pragma unroll
  for (int kc = 0; kc < 4; ++kc) qf[kc] = ld8(&Q[qrow * 2048 + h * 128 + kc * 32 + g * 8]);
  f32x4 O[8] = {};
  float m = -1e30f, lsum = 0.f;
  const unsigned short* Kbase = Kg + (size_t)b * 2048 * 2048 + h * 128;
  const unsigned short* VTb = VT + (size_t)(b * 16 + h) * 128 * 2048;
  for (int kt = 0; kt < 2048; kt += 64) {
    __syncthreads();
#pragma unroll
    for (int j = 0; j < 4; ++j) {
      int c = j * 256 + tid;
      int key = c >> 4, cc = c & 15;  // K tile: 64 x 128
      *reinterpret_cast<us8*>(&Ks[key * 128 + ((cc ^ (key & 7)) * 8)]) =
          *reinterpret_cast<const us8*>(&Kbase[(size_t)(kt + key) * 2048 + cc * 8]);
      int d = c >> 3, cc2 = c & 7;    // VT tile: 128 x 64
      *reinterpret_cast<us8*>(&VTs[d * 64 + ((cc2 ^ (d & 7)) * 8)]) =
          *reinterpret_cast<const us8*>(&VTb[(size_t)d * 2048 + kt + cc2 * 8]);
    }
    __syncthreads();
    // S = K . Q^T (swapped): lane holds q=l16, keys t*16 + g*4 + r
    f32x4 st[4] = {};
#pragma unroll
    for (int t = 0; t < 4; ++t) {
      int key = t * 16 + l16;
      int swz = (key & 7) << 3;
#pragma unroll
      for (int kc = 0; kc < 4; ++kc) {
        us8 kf = ld8(&Ks[key * 128 + ((kc * 32 + g * 8) ^ swz)]);
        mfma_bf16(st[t], kf, qf[kc]);
      }
    }
    float sv[4][4];
    float smax = -1e30f;
#pragma unroll
    for (int t = 0; t < 4; ++t)
#pragma unroll
      for (int r = 0; r < 4; ++r) {
        sv[t][r] = st[t][r] * SCALE;
        smax = fmaxf(smax, sv[t][r]);
      }
    smax = fmaxf(smax, __shfl_xor(smax, 16));
    smax = fmaxf(smax, __shfl_xor(smax, 32));
    float mnew = fmaxf(m, smax);
    float fac = __expf(m - mnew);
    float psum = 0.f;
#pragma unroll
    for (int t = 0; t < 4; ++t)
#pragma unroll
      for (int r = 0; r < 4; ++r) {
        sv[t][r] = __expf(sv[t][r] - mnew);
        psum += sv[t][r];
      }
    psum += __shfl_xor(psum, 16);
    psum += __shfl_xor(psum, 32);
    lsum = lsum * fac + psum;
    m = mnew;
#pragma unroll
    for (int r = 0; r < 4; ++r) {
      float fr = __shfl(fac, g * 4 + r);
#pragma unroll
      for (int n0 = 0; n0 < 8; ++n0) O[n0][r] *= fr;
    }
    // P -> LDS (per-wave region, swizzled), read back as A-fragments
    unsigned* P32 = reinterpret_cast<unsigned*>(&Ps[w][0]);
    int qswz = (l16 & 7) << 3;
#pragma unroll
    for (int t = 0; t < 4; ++t)
#pragma unroll
      for (int pp = 0; pp < 2; ++pp) {
        int key = t * 16 + g * 4 + pp * 2;
        unsigned pack = (unsigned)f2bf(sv[t][pp * 2]) | ((unsigned)f2bf(sv[t][pp * 2 + 1]) << 16);
        int elem = l16 * 64 + (key ^ qswz);
        P32[elem >> 1] = pack;
      }
    us8 pf[2];
#pragma unroll
    for (int kc = 0; kc < 2; ++kc)
      pf[kc] = ld8(&Ps[w][l16 * 64 + ((kc * 32 + g * 8) ^ qswz)]);
#pragma unroll
    for (int n0 = 0; n0 < 8; ++n0) {
      int d = n0 * 16 + l16;
      int dswz = (d & 7) << 3;
#pragma unroll
      for (int kc = 0; kc < 2; ++kc) {
        us8 vf = ld8(&VTs[d * 64 + ((kc * 32 + g * 8) ^ dswz)]);
        mfma_bf16(O[n0], pf[kc], vf);
      }
    }
  }
  float inv = 1.0f / lsum;
#pragma unroll
  for (int r = 0; r < 4; ++r) {
    float ir = __shfl(inv, g * 4 + r);
    size_t row = (size_t)b * 2048 + qt * 64 + w * 16 + g * 4 + r;
#pragma unroll
    for (int n0 = 0; n0 < 8; ++n0)
      Aout[row * 2048 + h * 128 + n0 * 16 + l16] = f2bf(O[n0][r] * ir);
  }
}

extern "C" void kernel_launch(void* const* d_in, const int* in_sizes, int n_in, void* d_out,
                              int out_size, void* d_ws, size_t ws_size, hipStream_t stream) {
  (void)in_sizes; (void)n_in; (void)out_size; (void)ws_size;
  constexpr int Mr = 4096;
  using US = unsigned short;
  const float* x        = (const float*)d_in[0];
  const float* w_down_q = (const float*)d_in[1];
  const float* b_down_q = (const float*)d_in[2];
  const float* w_up_q   = (const float*)d_in[3];
  const float* b_up_q   = (const float*)d_in[4];
  const float* w_down_kv= (const float*)d_in[5];
  const float* b_down_kv= (const float*)d_in[6];
  const float* w_up_k   = (const float*)d_in[7];
  const float* b_up_k   = (const float*)d_in[8];
  const float* w_up_v   = (const float*)d_in[9];
  const float* b_up_v   = (const float*)d_in[10];
  const float* wq_r     = (const float*)d_in[11];
  const float* bq_r     = (const float*)d_in[12];
  const float* wk_r     = (const float*)d_in[13];
  const float* bk_r     = (const float*)d_in[14];
  const float* wo       = (const float*)d_in[15];
  const float* bo       = (const float*)d_in[16];

  char* p = (char*)d_ws;
  auto alloc = [&](size_t bytes) { char* r = p; p += (bytes + 255) & ~(size_t)255; return r; };
  float* cosT = (float*)alloc((size_t)2048 * 1024 * 4);
  float* sinT = (float*)alloc((size_t)2048 * 1024 * 4);
  US* xb   = (US*)alloc((size_t)Mr * 2048 * 2);
  US* wdq  = (US*)alloc((size_t)1536 * 2048 * 2);
  US* wuq  = (US*)alloc((size_t)2048 * 1536 * 2);
  US* wqr  = (US*)alloc((size_t)2048 * 1536 * 2);
  US* wdkv = (US*)alloc((size_t)512 * 2048 * 2);
  US* wuk  = (US*)alloc((size_t)2048 * 512 * 2);
  US* wuv  = (US*)alloc((size_t)2048 * 512 * 2);
  US* wkr  = (US*)alloc((size_t)2048 * 512 * 2);
  US* wob  = (US*)alloc((size_t)2048 * 2048 * 2);
  US* ctq  = (US*)alloc((size_t)Mr * 1536 * 2);
  US* ctkv = (US*)alloc((size_t)Mr * 512 * 2);
  US* t1   = (US*)alloc((size_t)Mr * 2048 * 2);
  US* t2   = (US*)alloc((size_t)Mr * 2048 * 2);
  US* qb   = (US*)alloc((size_t)Mr * 2048 * 2);
  US* kb   = (US*)alloc((size_t)Mr * 2048 * 2);
  US* vtb  = (US*)alloc((size_t)Mr * 2048 * 2);

  auto cvt = [&](const float* s, US* dptr, size_t n) {
    int n4 = (int)(n / 4);
    k_cvt<<<dim3((n4 + 255) / 256), dim3(256), 0, stream>>>(s, dptr, n4);
  };
  cvt(x, xb, (size_t)Mr * 2048);
  cvt(w_down_q, wdq, (size_t)1536 * 2048);
  cvt(w_up_q, wuq, (size_t)2048 * 1536);
  cvt(wq_r, wqr, (size_t)2048 * 1536);
  cvt(w_down_kv, wdkv, (size_t)512 * 2048);
  cvt(w_up_k, wuk, (size_t)2048 * 512);
  cvt(w_up_v, wuv, (size_t)2048 * 512);
  cvt(wk_r, wkr, (size_t)2048 * 512);
  cvt(wo, wob, (size_t)2048 * 2048);
  k_freqs<<<dim3((2048 * 1024 + 255) / 256), dim3(256), 0, stream>>>(cosT, sinT);

  auto gemm_bf = [&](const US* A, const US* B, const float* bias, US* C, int M, int N, int K) {
    k_gemm_bt<false><<<dim3(N / 128, M / 128), dim3(256), 0, stream>>>(A, B, bias, (void*)C, M, N, K);
  };
  // Q path
  gemm_bf(xb, wdq, b_down_q, ctq, Mr, 1536, 2048);
  gemm_bf(ctq, wuq, b_up_q, t1, Mr, 2048, 1536);
  gemm_bf(ctq, wqr, bq_r, t2, Mr, 2048, 1536);
  k_rope_combine<<<dim3((4096 * 1024 + 255) / 256), dim3(256), 0, stream>>>(t1, t2, cosT, sinT, qb);
  // KV path
  gemm_bf(xb, wdkv, b_down_kv, ctkv, Mr, 512, 2048);
  gemm_bf(ctkv, wuk, b_up_k, t1, Mr, 2048, 512);
  gemm_bf(ctkv, wkr, bk_r, t2, Mr, 2048, 512);
  k_rope_combine<<<dim3((4096 * 1024 + 255) / 256), dim3(256), 0, stream>>>(t1, t2, cosT, sinT, kb);
  gemm_bf(ctkv, wuv, b_up_v, t1, Mr, 2048, 512);
  k_transpose_v<<<dim3(64, 128), dim3(256), 0, stream>>>(t1, vtb);
  // attention -> t2
  k_attn<<<dim3(32, 16, 2), dim3(256), 0, stream>>>(qb, kb, vtb, t2);
  // output projection (f32 out)
  k_gemm_bt<true><<<dim3(2048 / 128, Mr / 128), dim3(256), 0, stream>>>(t2, wob, bo, d_out, Mr,
                                                                        2048, 2048);
}

// Round 3
// 462.577 us; speedup vs baseline: 1.1304x; 1.1304x over previous
//
#include <hip/hip_runtime.h>

typedef float f32x4 __attribute__((ext_vector_type(4)));
typedef unsigned short us8 __attribute__((ext_vector_type(8)));

#define DEVINL __device__ __forceinline__

DEVINL unsigned short f2bf(float f) {
  unsigned u = __builtin_bit_cast(unsigned, f);
  u += 0x7fffu + ((u >> 16) & 1u);
  return (unsigned short)(u >> 16);
}
DEVINL float bf2f(unsigned short b) { return __builtin_bit_cast(float, ((unsigned)b) << 16); }
DEVINL us8 ld8(const unsigned short* p) { return *reinterpret_cast<const us8*>(p); }
DEVINL void mfma_bf16(f32x4& acc, us8 a, us8 b) {
  asm("v_mfma_f32_16x16x32_bf16 %0, %1, %2, %0" : "+v"(acc) : "v"(a), "v"(b));
}
DEVINL unsigned cvtpk_bf16(float lo, float hi) {
  unsigned r;
  asm("v_cvt_pk_bf16_f32 %0, %1, %2" : "=v"(r) : "v"(lo), "v"(hi));
  return r;
}
// async global->LDS, 16B per lane; LDS dest = base + lane*16 (wave-uniform base)
DEVINL void gld16(const void* g, void* l) {
  __builtin_amdgcn_global_load_lds((const __attribute__((address_space(1))) void*)g,
                                   (__attribute__((address_space(3))) void*)l, 16, 0, 0);
}

// ---------------- elementwise convert fp32 -> bf16 (x4 vectorized) ----------------
__global__ void k_cvt(const float* __restrict__ in, unsigned short* __restrict__ out, int n4) {
  int i = blockIdx.x * 256 + threadIdx.x;
  if (i >= n4) return;
  float4 v = reinterpret_cast<const float4*>(in)[i];
  unsigned lo = (unsigned)f2bf(v.x) | ((unsigned)f2bf(v.y) << 16);
  unsigned hi = (unsigned)f2bf(v.z) | ((unsigned)f2bf(v.w) << 16);
  reinterpret_cast<uint2*>(out)[i] = make_uint2(lo, hi);
}

// ---------------- RoPE freq tables (replicates reference fp32 semantics) ----------------
__global__ void k_freqs(float* __restrict__ cosT, float* __restrict__ sinT) {
  int idx = blockIdx.x * 256 + threadIdx.x;
  if (idx >= 2048 * 1024) return;
  int s = idx >> 10, i = idx & 1023;
  float e = (float)(2 * i);
  float pw = powf(10000.0f, e);  // overflows to inf for large e -> tn = 0, matches fp32 ref
  float tn = 1.0f / (pw / 2048.0f);
  float ang = (float)s * tn;
  cosT[idx] = cosf(ang);
  sinT[idx] = sinf(ang);
}

// ---------------- GEMM: C[M,N] = A[M,K] * B[N,K]^T + bias (m97 structure) ----------------
template <bool OUTF32>
__global__ __launch_bounds__(256) void k_gemm_bt(const unsigned short* __restrict__ A,
                                                 const unsigned short* __restrict__ B,
                                                 const float* __restrict__ bias,
                                                 void* __restrict__ Cout, int M, int N, int K) {
  __shared__ unsigned short As[128 * 32];
  __shared__ unsigned short Bs[128 * 32];
  const int tid = threadIdx.x, lane = tid & 63, w = tid >> 6;
  const int g = lane >> 4, l16 = lane & 15;
  const int bn = blockIdx.x, bm = blockIdx.y;
  const int wm = w >> 1, wn = w & 1;
  f32x4 acc[4][4] = {};
  const unsigned short* Arow = A + (size_t)bm * 128 * K;
  const unsigned short* Brow = B + (size_t)bn * 128 * K;
  for (int kt = 0; kt < K; kt += 32) {
    __syncthreads();
#pragma unroll
    for (int j = 0; j < 2; ++j) {
      int c = (j * 4 + w) * 64 + lane;  // 16B chunk id in [0,512)
      int row = c >> 2, c4 = c & 3;     // A/B tile: 128 rows x 4 chunks
      gld16(&Arow[(size_t)row * K + kt + c4 * 8], &As[(j * 4 + w) * 64 * 8]);
      gld16(&Brow[(size_t)row * K + kt + c4 * 8], &Bs[(j * 4 + w) * 64 * 8]);
    }
    __syncthreads();
    us8 af[4], bfg[4];
#pragma unroll
    for (int mm = 0; mm < 4; ++mm) af[mm] = ld8(&As[(wm * 64 + mm * 16 + l16) * 32 + g * 8]);
#pragma unroll
    for (int nn = 0; nn < 4; ++nn) bfg[nn] = ld8(&Bs[(wn * 64 + nn * 16 + l16) * 32 + g * 8]);
#pragma unroll
    for (int mm = 0; mm < 4; ++mm)
#pragma unroll
      for (int nn = 0; nn < 4; ++nn) mfma_bf16(acc[mm][nn], af[mm], bfg[nn]);
  }
#pragma unroll
  for (int nn = 0; nn < 4; ++nn) {
    int col = bn * 128 + wn * 64 + nn * 16 + l16;
    float bv = bias[col];
#pragma unroll
    for (int mm = 0; mm < 4; ++mm) {
      int row0 = bm * 128 + wm * 64 + mm * 16 + g * 4;
#pragma unroll
      for (int r = 0; r < 4; ++r) {
        float vv = acc[mm][nn][r] + bv;
        if (OUTF32)
          reinterpret_cast<float*>(Cout)[(size_t)(row0 + r) * N + col] = vv;
        else
          reinterpret_cast<unsigned short*>(Cout)[(size_t)(row0 + r) * N + col] = f2bf(vv);
      }
    }
  }
}

// ---------------- q/k = ct + rope(rl) ----------------
__global__ void k_rope_combine(const unsigned short* __restrict__ ct,
                               const unsigned short* __restrict__ rl,
                               const float* __restrict__ cosT, const float* __restrict__ sinT,
                               unsigned short* __restrict__ outp) {
  int pidx = blockIdx.x * 256 + threadIdx.x;  // pair index
  if (pidx >= 4096 * 1024) return;
  int row = pidx >> 10, i = pidx & 1023;
  int s = row & 2047;
  float c = cosT[s * 1024 + i], sn = sinT[s * 1024 + i];
  int base = row * 2048 + i * 2;
  float xe = bf2f(rl[base]), xo = bf2f(rl[base + 1]);
  float re = xe * c - xo * sn;
  float im = xe * sn + xo * c;
  float q0 = bf2f(ct[base]) + re;
  float q1 = bf2f(ct[base + 1]) + im;
  unsigned pack = (unsigned)f2bf(q0) | ((unsigned)f2bf(q1) << 16);
  *reinterpret_cast<unsigned*>(&outp[base]) = pack;
}

// ---------------- V transpose: v[4096][2048] -> vt[b][h][d][s] ----------------
__global__ __launch_bounds__(256) void k_transpose_v(const unsigned short* __restrict__ v,
                                                     unsigned short* __restrict__ vt) {
  __shared__ unsigned short t[32][33];
  int tx = threadIdx.x & 31, ty = threadIdx.x >> 5;
  int r0 = blockIdx.y * 32, c0 = blockIdx.x * 32;
#pragma unroll
  for (int jj = 0; jj < 4; ++jj)
    t[ty * 4 + jj][tx] = v[(size_t)(r0 + ty * 4 + jj) * 2048 + c0 + tx];
  __syncthreads();
  int b = r0 >> 11;
#pragma unroll
  for (int jj = 0; jj < 4; ++jj) {
    int colc = c0 + ty * 4 + jj;
    size_t orow = (size_t)(b * 16 + (colc >> 7)) * 128 + (colc & 127);
    vt[orow * 2048 + (r0 & 2047) + tx] = t[tx][ty * 4 + jj];
  }
}

// ---------------- flash attention: 4 waves x 32 q-rows (2 groups of 16), KV tile 64 ------
// K LDS layout: 16B-chunk (key, cp) holds global chunk (cp ^ (key&7))  [XOR swizzle,
// applied by pre-swizzling the global source so global_load_lds can write linearly]
// VT LDS layout: chunk (d, c2) holds global chunk (c2 ^ (d&7))
__global__ __launch_bounds__(256, 2) void k_attn(const unsigned short* __restrict__ Q,
                                                 const unsigned short* __restrict__ Kg,
                                                 const unsigned short* __restrict__ VT,
                                                 unsigned short* __restrict__ Aout) {
  __shared__ unsigned short Ks[64 * 128];
  __shared__ unsigned short VTs[128 * 64];
  __shared__ unsigned short Ps[4][2][16 * 64];
  const int tid = threadIdx.x, lane = tid & 63, w = tid >> 6;
  const int g = lane >> 4, l16 = lane & 15;
  const int qt = blockIdx.x, h = blockIdx.y, b = blockIdx.z;
  const float SC2 = 0.08838834764831845f * 1.4426950408889634f;  // (1/sqrt(128))*log2(e)
  us8 qf[2][4];
#pragma unroll
  for (int qg = 0; qg < 2; ++qg) {
    const size_t qrow = (size_t)b * 2048 + qt * 128 + w * 32 + qg * 16 + l16;
#pragma unroll
    for (int kc = 0; kc < 4; ++kc)
      qf[qg][kc] = ld8(&Q[qrow * 2048 + h * 128 + kc * 32 + g * 8]);
  }
  f32x4 O[2][8] = {};
  float mq[2] = {-1e30f, -1e30f}, lq[2] = {0.f, 0.f};
  const unsigned short* Kbase = Kg + (size_t)b * 2048 * 2048 + h * 128;
  const unsigned short* VTb = VT + (size_t)(b * 16 + h) * 128 * 2048;
  for (int kt = 0; kt < 2048; kt += 64) {
    __syncthreads();
#pragma unroll
    for (int j = 0; j < 4; ++j) {
      int ch = (j * 4 + w) * 64 + lane;  // 16B chunk id in [0,1024)
      int key = ch >> 4, cp = ch & 15;   // K tile: 64 rows x 16 chunks  (FIXED geometry)
      gld16(&Kbase[(size_t)(kt + key) * 2048 + (size_t)((cp ^ (key & 7)) * 8)],
            &Ks[(j * 4 + w) * 64 * 8]);
      int d = ch >> 3, c2 = ch & 7;      // VT tile: 128 rows x 8 chunks
      gld16(&VTb[(size_t)d * 2048 + kt + (size_t)((c2 ^ (d & 7)) * 8)],
            &VTs[(j * 4 + w) * 64 * 8]);
    }
    __syncthreads();
    // S = K . Q^T (swapped): lane(g,l16) holds S[key=t*16+g*4+r][q=l16] for each q-group
    f32x4 st[2][4] = {};
    __builtin_amdgcn_s_setprio(1);
#pragma unroll
    for (int t = 0; t < 4; ++t) {
      int key = t * 16 + l16;
      int swz = (key & 7) << 3;
#pragma unroll
      for (int kc = 0; kc < 4; ++kc) {
        us8 kf = ld8(&Ks[key * 128 + ((kc * 32 + g * 8) ^ swz)]);
        mfma_bf16(st[0][t], kf, qf[0][kc]);
        mfma_bf16(st[1][t], kf, qf[1][kc]);
      }
    }
    __builtin_amdgcn_s_setprio(0);
    const int qswz = (l16 & 7) << 3;
#pragma unroll
    for (int qg = 0; qg < 2; ++qg) {
      float sv[16];
      float smax = -1e30f;
#pragma unroll
      for (int t = 0; t < 4; ++t)
#pragma unroll
        for (int r = 0; r < 4; ++r) {
          sv[t * 4 + r] = st[qg][t][r] * SC2;
          smax = fmaxf(smax, sv[t * 4 + r]);
        }
      smax = fmaxf(smax, __shfl_xor(smax, 16));
      smax = fmaxf(smax, __shfl_xor(smax, 32));
      float mn = fmaxf(mq[qg], smax);
      float fac = exp2f(mq[qg] - mn);
      float ps = 0.f;
#pragma unroll
      for (int i = 0; i < 16; ++i) {
        sv[i] = exp2f(sv[i] - mn);
        ps += sv[i];
      }
      ps += __shfl_xor(ps, 16);
      ps += __shfl_xor(ps, 32);
      lq[qg] = lq[qg] * fac + ps;
      mq[qg] = mn;
#pragma unroll
      for (int r = 0; r < 4; ++r) {
        float fr = __shfl(fac, g * 4 + r);
#pragma unroll
        for (int n0 = 0; n0 < 8; ++n0) O[qg][n0][r] *= fr;
      }
      // P -> LDS (per-wave, per-group region; swizzled by q-row)
      unsigned* P32 = reinterpret_cast<unsigned*>(&Ps[w][qg][0]);
#pragma unroll
      for (int t = 0; t < 4; ++t)
#pragma unroll
        for (int pp = 0; pp < 2; ++pp) {
          int key = t * 16 + g * 4 + pp * 2;
          unsigned pk = cvtpk_bf16(sv[t * 4 + pp * 2], sv[t * 4 + pp * 2 + 1]);
          int elem = l16 * 64 + (key ^ qswz);
          P32[elem >> 1] = pk;
        }
    }
    us8 pf[2][2];
#pragma unroll
    for (int qg = 0; qg < 2; ++qg)
#pragma unroll
      for (int kc = 0; kc < 2; ++kc)
        pf[qg][kc] = ld8(&Ps[w][qg][l16 * 64 + ((kc * 32 + g * 8) ^ qswz)]);
    __builtin_amdgcn_s_setprio(1);
#pragma unroll
    for (int n0 = 0; n0 < 8; ++n0) {
      int d = n0 * 16 + l16;
      int dsw = (d & 7) << 3;
#pragma unroll
      for (int kc = 0; kc < 2; ++kc) {
        us8 vf = ld8(&VTs[d * 64 + ((kc * 32 + g * 8) ^ dsw)]);
        mfma_bf16(O[0][n0], pf[0][kc], vf);
        mfma_bf16(O[1][n0], pf[1][kc], vf);
      }
    }
    __builtin_amdgcn_s_setprio(0);
  }
#pragma unroll
  for (int qg = 0; qg < 2; ++qg) {
    float inv = 1.0f / lq[qg];
#pragma unroll
    for (int r = 0; r < 4; ++r) {
      float ir = __shfl(inv, g * 4 + r);
      size_t row = (size_t)b * 2048 + qt * 128 + w * 32 + qg * 16 + g * 4 + r;
#pragma unroll
      for (int n0 = 0; n0 < 8; ++n0)
        Aout[row * 2048 + h * 128 + n0 * 16 + l16] = f2bf(O[qg][n0][r] * ir);
    }
  }
}

extern "C" void kernel_launch(void* const* d_in, const int* in_sizes, int n_in, void* d_out,
                              int out_size, void* d_ws, size_t ws_size, hipStream_t stream) {
  (void)in_sizes; (void)n_in; (void)out_size; (void)ws_size;
  constexpr int Mr = 4096;
  using US = unsigned short;
  const float* x        = (const float*)d_in[0];
  const float* w_down_q = (const float*)d_in[1];
  const float* b_down_q = (const float*)d_in[2];
  const float* w_up_q   = (const float*)d_in[3];
  const float* b_up_q   = (const float*)d_in[4];
  const float* w_down_kv= (const float*)d_in[5];
  const float* b_down_kv= (const float*)d_in[6];
  const float* w_up_k   = (const float*)d_in[7];
  const float* b_up_k   = (const float*)d_in[8];
  const float* w_up_v   = (const float*)d_in[9];
  const float* b_up_v   = (const float*)d_in[10];
  const float* wq_r     = (const float*)d_in[11];
  const float* bq_r     = (const float*)d_in[12];
  const float* wk_r     = (const float*)d_in[13];
  const float* bk_r     = (const float*)d_in[14];
  const float* wo       = (const float*)d_in[15];
  const float* bo       = (const float*)d_in[16];

  char* p = (char*)d_ws;
  auto alloc = [&](size_t bytes) { char* r = p; p += (bytes + 255) & ~(size_t)255; return r; };
  float* cosT = (float*)alloc((size_t)2048 * 1024 * 4);
  float* sinT = (float*)alloc((size_t)2048 * 1024 * 4);
  US* xb   = (US*)alloc((size_t)Mr * 2048 * 2);
  US* wdq  = (US*)alloc((size_t)1536 * 2048 * 2);
  US* wuq  = (US*)alloc((size_t)2048 * 1536 * 2);
  US* wqr  = (US*)alloc((size_t)2048 * 1536 * 2);
  US* wdkv = (US*)alloc((size_t)512 * 2048 * 2);
  US* wuk  = (US*)alloc((size_t)2048 * 512 * 2);
  US* wuv  = (US*)alloc((size_t)2048 * 512 * 2);
  US* wkr  = (US*)alloc((size_t)2048 * 512 * 2);
  US* wob  = (US*)alloc((size_t)2048 * 2048 * 2);
  US* ctq  = (US*)alloc((size_t)Mr * 1536 * 2);
  US* ctkv = (US*)alloc((size_t)Mr * 512 * 2);
  US* t1   = (US*)alloc((size_t)Mr * 2048 * 2);
  US* t2   = (US*)alloc((size_t)Mr * 2048 * 2);
  US* qb   = (US*)alloc((size_t)Mr * 2048 * 2);
  US* kb   = (US*)alloc((size_t)Mr * 2048 * 2);
  US* vtb  = (US*)alloc((size_t)Mr * 2048 * 2);

  auto cvt = [&](const float* s, US* dptr, size_t n) {
    int n4 = (int)(n / 4);
    k_cvt<<<dim3((n4 + 255) / 256), dim3(256), 0, stream>>>(s, dptr, n4);
  };
  cvt(x, xb, (size_t)Mr * 2048);
  cvt(w_down_q, wdq, (size_t)1536 * 2048);
  cvt(w_up_q, wuq, (size_t)2048 * 1536);
  cvt(wq_r, wqr, (size_t)2048 * 1536);
  cvt(w_down_kv, wdkv, (size_t)512 * 2048);
  cvt(w_up_k, wuk, (size_t)2048 * 512);
  cvt(w_up_v, wuv, (size_t)2048 * 512);
  cvt(wk_r, wkr, (size_t)2048 * 512);
  cvt(wo, wob, (size_t)2048 * 2048);
  k_freqs<<<dim3((2048 * 1024 + 255) / 256), dim3(256), 0, stream>>>(cosT, sinT);

  auto gemm_bf = [&](const US* A, const US* B, const float* bias, US* C, int M, int N, int K) {
    k_gemm_bt<false><<<dim3(N / 128, M / 128), dim3(256), 0, stream>>>(A, B, bias, (void*)C, M, N, K);
  };
  // Q path
  gemm_bf(xb, wdq, b_down_q, ctq, Mr, 1536, 2048);
  gemm_bf(ctq, wuq, b_up_q, t1, Mr, 2048, 1536);
  gemm_bf(ctq, wqr, bq_r, t2, Mr, 2048, 1536);
  k_rope_combine<<<dim3((4096 * 1024 + 255) / 256), dim3(256), 0, stream>>>(t1, t2, cosT, sinT, qb);
  // KV path
  gemm_bf(xb, wdkv, b_down_kv, ctkv, Mr, 512, 2048);
  gemm_bf(ctkv, wuk, b_up_k, t1, Mr, 2048, 512);
  gemm_bf(ctkv, wkr, bk_r, t2, Mr, 2048, 512);
  k_rope_combine<<<dim3((4096 * 1024 + 255) / 256), dim3(256), 0, stream>>>(t1, t2, cosT, sinT, kb);
  gemm_bf(ctkv, wuv, b_up_v, t1, Mr, 2048, 512);
  k_transpose_v<<<dim3(64, 128), dim3(256), 0, stream>>>(t1, vtb);
  // attention -> t2
  k_attn<<<dim3(16, 16, 2), dim3(256), 0, stream>>>(qb, kb, vtb, t2);
  // output projection (f32 out)
  k_gemm_bt<true><<<dim3(2048 / 128, Mr / 128), dim3(256), 0, stream>>>(t2, wob, bo, d_out, Mr,
                                                                        2048, 2048);
}

// Round 4
// 412.031 us; speedup vs baseline: 1.2690x; 1.1227x over previous
//
#include <hip/hip_runtime.h>

typedef float f32x4 __attribute__((ext_vector_type(4)));
typedef unsigned short us8 __attribute__((ext_vector_type(8)));

#define DEVINL __device__ __forceinline__

DEVINL unsigned short f2bf(float f) {
  unsigned u = __builtin_bit_cast(unsigned, f);
  u += 0x7fffu + ((u >> 16) & 1u);
  return (unsigned short)(u >> 16);
}
DEVINL float bf2f(unsigned short b) { return __builtin_bit_cast(float, ((unsigned)b) << 16); }
DEVINL us8 ld8(const unsigned short* p) { return *reinterpret_cast<const us8*>(p); }
DEVINL void mfma_bf16(f32x4& acc, us8 a, us8 b) {
  asm("v_mfma_f32_16x16x32_bf16 %0, %1, %2, %0" : "+v"(acc) : "v"(a), "v"(b));
}
DEVINL unsigned cvtpk_bf16(float lo, float hi) {
  unsigned r;
  asm("v_cvt_pk_bf16_f32 %0, %1, %2" : "=v"(r) : "v"(lo), "v"(hi));
  return r;
}
// async global->LDS, 16B per lane; LDS dest = base + lane*16 (wave-uniform base)
DEVINL void gld16(const void* g, void* l) {
  __builtin_amdgcn_global_load_lds((const __attribute__((address_space(1))) void*)g,
                                   (__attribute__((address_space(3))) void*)l, 16, 0, 0);
}

// ---------------- elementwise convert fp32 -> bf16 (x4 vectorized) ----------------
__global__ void k_cvt(const float* __restrict__ in, unsigned short* __restrict__ out, int n4) {
  int i = blockIdx.x * 256 + threadIdx.x;
  if (i >= n4) return;
  float4 v = reinterpret_cast<const float4*>(in)[i];
  unsigned lo = (unsigned)f2bf(v.x) | ((unsigned)f2bf(v.y) << 16);
  unsigned hi = (unsigned)f2bf(v.z) | ((unsigned)f2bf(v.w) << 16);
  reinterpret_cast<uint2*>(out)[i] = make_uint2(lo, hi);
}

// ---------------- RoPE freq tables (replicates reference fp32 semantics) ----------------
__global__ void k_freqs(float* __restrict__ cosT, float* __restrict__ sinT) {
  int idx = blockIdx.x * 256 + threadIdx.x;
  if (idx >= 2048 * 1024) return;
  int s = idx >> 10, i = idx & 1023;
  float e = (float)(2 * i);
  float pw = powf(10000.0f, e);  // overflows to inf for large e -> tn = 0, matches fp32 ref
  float tn = 1.0f / (pw / 2048.0f);
  float ang = (float)s * tn;
  cosT[idx] = cosf(ang);
  sinT[idx] = sinf(ang);
}

// -------- GEMM: C[M,N] = A[M,K] (row stride lda) * B[N,K]^T + bias  (m97 + XCD swizzle) -----
template <bool OUTF32>
__global__ __launch_bounds__(256) void k_gemm_bt(const unsigned short* __restrict__ A,
                                                 const unsigned short* __restrict__ B,
                                                 const float* __restrict__ bias,
                                                 void* __restrict__ Cout, int M, int N, int K,
                                                 int lda) {
  __shared__ unsigned short As[128 * 32];
  __shared__ unsigned short Bs[128 * 32];
  // XCD-aware chunked swizzle (grid size always a multiple of 8 here)
  const int nwg = gridDim.x;
  const int q8 = nwg >> 3;
  const int orig = blockIdx.x;
  const int wgid = (orig & 7) * q8 + (orig >> 3);
  const int nbn = N >> 7;
  const int bn = wgid % nbn, bm = wgid / nbn;
  const int tid = threadIdx.x, lane = tid & 63, w = tid >> 6;
  const int g = lane >> 4, l16 = lane & 15;
  const int wm = w >> 1, wn = w & 1;
  f32x4 acc[4][4] = {};
  const unsigned short* Arow = A + (size_t)bm * 128 * lda;
  const unsigned short* Brow = B + (size_t)bn * 128 * K;
  for (int kt = 0; kt < K; kt += 32) {
    __syncthreads();
#pragma unroll
    for (int j = 0; j < 2; ++j) {
      int c = (j * 4 + w) * 64 + lane;  // 16B chunk id in [0,512)
      int row = c >> 2, c4 = c & 3;     // A/B tile: 128 rows x 4 chunks
      gld16(&Arow[(size_t)row * lda + kt + c4 * 8], &As[(j * 4 + w) * 64 * 8]);
      gld16(&Brow[(size_t)row * K + kt + c4 * 8], &Bs[(j * 4 + w) * 64 * 8]);
    }
    __syncthreads();
    us8 af[4], bfg[4];
#pragma unroll
    for (int mm = 0; mm < 4; ++mm) af[mm] = ld8(&As[(wm * 64 + mm * 16 + l16) * 32 + g * 8]);
#pragma unroll
    for (int nn = 0; nn < 4; ++nn) bfg[nn] = ld8(&Bs[(wn * 64 + nn * 16 + l16) * 32 + g * 8]);
#pragma unroll
    for (int mm = 0; mm < 4; ++mm)
#pragma unroll
      for (int nn = 0; nn < 4; ++nn) mfma_bf16(acc[mm][nn], af[mm], bfg[nn]);
  }
#pragma unroll
  for (int nn = 0; nn < 4; ++nn) {
    int col = bn * 128 + wn * 64 + nn * 16 + l16;
    float bv = bias[col];
#pragma unroll
    for (int mm = 0; mm < 4; ++mm) {
      int row0 = bm * 128 + wm * 64 + mm * 16 + g * 4;
#pragma unroll
      for (int r = 0; r < 4; ++r) {
        float vv = acc[mm][nn][r] + bv;
        if (OUTF32)
          reinterpret_cast<float*>(Cout)[(size_t)(row0 + r) * N + col] = vv;
        else
          reinterpret_cast<unsigned short*>(Cout)[(size_t)(row0 + r) * N + col] = f2bf(vv);
      }
    }
  }
}

// ---- q/k = ct + rope(rl): src row holds [ct (2048) | rl (2048) | ...], width ldin ----
__global__ void k_rope_combine(const unsigned short* __restrict__ src, int ldin,
                               const float* __restrict__ cosT, const float* __restrict__ sinT,
                               unsigned short* __restrict__ outp) {
  int pidx = blockIdx.x * 256 + threadIdx.x;  // pair index
  if (pidx >= 4096 * 1024) return;
  int row = pidx >> 10, i = pidx & 1023;
  int s = row & 2047;
  float c = cosT[s * 1024 + i], sn = sinT[s * 1024 + i];
  const unsigned short* rp = src + (size_t)row * ldin;
  float xe = bf2f(rp[2048 + 2 * i]), xo = bf2f(rp[2048 + 2 * i + 1]);
  float re = xe * c - xo * sn;
  float im = xe * sn + xo * c;
  float q0 = bf2f(rp[2 * i]) + re;
  float q1 = bf2f(rp[2 * i + 1]) + im;
  unsigned pack = (unsigned)f2bf(q0) | ((unsigned)f2bf(q1) << 16);
  *reinterpret_cast<unsigned*>(&outp[(size_t)row * 2048 + 2 * i]) = pack;
}

// ---------------- V transpose: v[4096][<=2048 cols of width ld] -> vt[b][h][d][s] ----------------
__global__ __launch_bounds__(256) void k_transpose_v(const unsigned short* __restrict__ v, int ld,
                                                     unsigned short* __restrict__ vt) {
  __shared__ unsigned short t[32][33];
  int tx = threadIdx.x & 31, ty = threadIdx.x >> 5;
  int r0 = blockIdx.y * 32, c0 = blockIdx.x * 32;
#pragma unroll
  for (int jj = 0; jj < 4; ++jj)
    t[ty * 4 + jj][tx] = v[(size_t)(r0 + ty * 4 + jj) * ld + c0 + tx];
  __syncthreads();
  int b = r0 >> 11;
#pragma unroll
  for (int jj = 0; jj < 4; ++jj) {
    int colc = c0 + ty * 4 + jj;
    size_t orow = (size_t)(b * 16 + (colc >> 7)) * 128 + (colc & 127);
    vt[orow * 2048 + (r0 & 2047) + tx] = t[tx][ty * 4 + jj];
  }
}

// ---------------- flash attention: 4 waves x 32 q-rows (2 groups of 16), KV tile 64 ------
__global__ __launch_bounds__(256, 2) void k_attn(const unsigned short* __restrict__ Q,
                                                 const unsigned short* __restrict__ Kg,
                                                 const unsigned short* __restrict__ VT,
                                                 unsigned short* __restrict__ Aout) {
  __shared__ unsigned short Ks[64 * 128];
  __shared__ unsigned short VTs[128 * 64];
  __shared__ unsigned short Ps[4][2][16 * 64];
  const int tid = threadIdx.x, lane = tid & 63, w = tid >> 6;
  const int g = lane >> 4, l16 = lane & 15;
  const int qt = blockIdx.x, h = blockIdx.y, b = blockIdx.z;
  const float SC2 = 0.08838834764831845f * 1.4426950408889634f;  // (1/sqrt(128))*log2(e)
  us8 qf[2][4];
#pragma unroll
  for (int qg = 0; qg < 2; ++qg) {
    const size_t qrow = (size_t)b * 2048 + qt * 128 + w * 32 + qg * 16 + l16;
#pragma unroll
    for (int kc = 0; kc < 4; ++kc)
      qf[qg][kc] = ld8(&Q[qrow * 2048 + h * 128 + kc * 32 + g * 8]);
  }
  f32x4 O[2][8] = {};
  float mq[2] = {-1e30f, -1e30f}, lq[2] = {0.f, 0.f};
  const unsigned short* Kbase = Kg + (size_t)b * 2048 * 2048 + h * 128;
  const unsigned short* VTb = VT + (size_t)(b * 16 + h) * 128 * 2048;
  for (int kt = 0; kt < 2048; kt += 64) {
    __syncthreads();
#pragma unroll
    for (int j = 0; j < 4; ++j) {
      int ch = (j * 4 + w) * 64 + lane;  // 16B chunk id in [0,1024)
      int key = ch >> 4, cp = ch & 15;   // K tile: 64 rows x 16 chunks
      gld16(&Kbase[(size_t)(kt + key) * 2048 + (size_t)((cp ^ (key & 7)) * 8)],
            &Ks[(j * 4 + w) * 64 * 8]);
      int d = ch >> 3, c2 = ch & 7;      // VT tile: 128 rows x 8 chunks
      gld16(&VTb[(size_t)d * 2048 + kt + (size_t)((c2 ^ (d & 7)) * 8)],
            &VTs[(j * 4 + w) * 64 * 8]);
    }
    __syncthreads();
    f32x4 st[2][4] = {};
    __builtin_amdgcn_s_setprio(1);
#pragma unroll
    for (int t = 0; t < 4; ++t) {
      int key = t * 16 + l16;
      int swz = (key & 7) << 3;
#pragma unroll
      for (int kc = 0; kc < 4; ++kc) {
        us8 kf = ld8(&Ks[key * 128 + ((kc * 32 + g * 8) ^ swz)]);
        mfma_bf16(st[0][t], kf, qf[0][kc]);
        mfma_bf16(st[1][t], kf, qf[1][kc]);
      }
    }
    __builtin_amdgcn_s_setprio(0);
    const int qswz = (l16 & 7) << 3;
#pragma unroll
    for (int qg = 0; qg < 2; ++qg) {
      float sv[16];
      float smax = -1e30f;
#pragma unroll
      for (int t = 0; t < 4; ++t)
#pragma unroll
        for (int r = 0; r < 4; ++r) {
          sv[t * 4 + r] = st[qg][t][r] * SC2;
          smax = fmaxf(smax, sv[t * 4 + r]);
        }
      smax = fmaxf(smax, __shfl_xor(smax, 16));
      smax = fmaxf(smax, __shfl_xor(smax, 32));
      float mn = fmaxf(mq[qg], smax);
      float fac = exp2f(mq[qg] - mn);
      float ps = 0.f;
#pragma unroll
      for (int i = 0; i < 16; ++i) {
        sv[i] = exp2f(sv[i] - mn);
        ps += sv[i];
      }
      ps += __shfl_xor(ps, 16);
      ps += __shfl_xor(ps, 32);
      lq[qg] = lq[qg] * fac + ps;
      mq[qg] = mn;
#pragma unroll
      for (int r = 0; r < 4; ++r) {
        float fr = __shfl(fac, g * 4 + r);
#pragma unroll
        for (int n0 = 0; n0 < 8; ++n0) O[qg][n0][r] *= fr;
      }
      unsigned* P32 = reinterpret_cast<unsigned*>(&Ps[w][qg][0]);
#pragma unroll
      for (int t = 0; t < 4; ++t)
#pragma unroll
        for (int pp = 0; pp < 2; ++pp) {
          int key = t * 16 + g * 4 + pp * 2;
          unsigned pk = cvtpk_bf16(sv[t * 4 + pp * 2], sv[t * 4 + pp * 2 + 1]);
          int elem = l16 * 64 + (key ^ qswz);
          P32[elem >> 1] = pk;
        }
    }
    us8 pf[2][2];
#pragma unroll
    for (int qg = 0; qg < 2; ++qg)
#pragma unroll
      for (int kc = 0; kc < 2; ++kc)
        pf[qg][kc] = ld8(&Ps[w][qg][l16 * 64 + ((kc * 32 + g * 8) ^ qswz)]);
    __builtin_amdgcn_s_setprio(1);
#pragma unroll
    for (int n0 = 0; n0 < 8; ++n0) {
      int d = n0 * 16 + l16;
      int dsw = (d & 7) << 3;
#pragma unroll
      for (int kc = 0; kc < 2; ++kc) {
        us8 vf = ld8(&VTs[d * 64 + ((kc * 32 + g * 8) ^ dsw)]);
        mfma_bf16(O[0][n0], pf[0][kc], vf);
        mfma_bf16(O[1][n0], pf[1][kc], vf);
      }
    }
    __builtin_amdgcn_s_setprio(0);
  }
#pragma unroll
  for (int qg = 0; qg < 2; ++qg) {
    float inv = 1.0f / lq[qg];
#pragma unroll
    for (int r = 0; r < 4; ++r) {
      float ir = __shfl(inv, g * 4 + r);
      size_t row = (size_t)b * 2048 + qt * 128 + w * 32 + qg * 16 + g * 4 + r;
#pragma unroll
      for (int n0 = 0; n0 < 8; ++n0)
        Aout[row * 2048 + h * 128 + n0 * 16 + l16] = f2bf(O[qg][n0][r] * ir);
    }
  }
}

extern "C" void kernel_launch(void* const* d_in, const int* in_sizes, int n_in, void* d_out,
                              int out_size, void* d_ws, size_t ws_size, hipStream_t stream) {
  (void)in_sizes; (void)n_in; (void)out_size; (void)ws_size;
  constexpr int Mr = 4096;
  using US = unsigned short;
  const float* x        = (const float*)d_in[0];
  const float* w_down_q = (const float*)d_in[1];
  const float* b_down_q = (const float*)d_in[2];
  const float* w_up_q   = (const float*)d_in[3];
  const float* b_up_q   = (const float*)d_in[4];
  const float* w_down_kv= (const float*)d_in[5];
  const float* b_down_kv= (const float*)d_in[6];
  const float* w_up_k   = (const float*)d_in[7];
  const float* b_up_k   = (const float*)d_in[8];
  const float* w_up_v   = (const float*)d_in[9];
  const float* b_up_v   = (const float*)d_in[10];
  const float* wq_r     = (const float*)d_in[11];
  const float* bq_r     = (const float*)d_in[12];
  const float* wk_r     = (const float*)d_in[13];
  const float* bk_r     = (const float*)d_in[14];
  const float* wo       = (const float*)d_in[15];
  const float* bo       = (const float*)d_in[16];

  char* p = (char*)d_ws;
  auto alloc = [&](size_t bytes) { char* r = p; p += (bytes + 255) & ~(size_t)255; return r; };
  float* cosT = (float*)alloc((size_t)2048 * 1024 * 4);
  float* sinT = (float*)alloc((size_t)2048 * 1024 * 4);
  US* xb        = (US*)alloc((size_t)Mr * 2048 * 2);      // aliased later by qb
  US* wcat_down = (US*)alloc((size_t)2048 * 2048 * 2);    // [wdq(1536); wdkv(512)] x 2048
  US* wcat_qup  = (US*)alloc((size_t)4096 * 1536 * 2);    // [wuq(2048); wqr(2048)] x 1536
  US* wcat_kvup = (US*)alloc((size_t)6144 * 512 * 2);     // [wuk; wkr; wuv] x 512
  US* wob       = (US*)alloc((size_t)2048 * 2048 * 2);
  US* ct        = (US*)alloc((size_t)Mr * 2048 * 2);      // [ctq(1536) | ctkv(512)]; aliased by aout
  US* big       = (US*)alloc((size_t)Mr * 6144 * 2);      // t12 (Mr x 4096) then kv3 (Mr x 6144)
  US* vtb       = (US*)alloc((size_t)Mr * 2048 * 2);
  float* bcat_down = (float*)alloc(2048 * 4);
  float* bcat_qup  = (float*)alloc(4096 * 4);
  float* bcat_kvup = (float*)alloc(6144 * 4);
  // aliases (lifetimes verified: producer of alias launches after last reader of original)
  US* qb   = xb;          // xb last read by G_down; qb written by combine_q (after G_qup)
  US* kb   = wcat_down;   // wcat_down+wcat_qup (20MB) dead after G_qup; kb needs 16MB
  US* t12  = big;
  US* kv3  = big;         // t12 dead after combine_q, which precedes G_kvup
  US* aout = ct;          // ct last read by G_kvup; attn writes aout afterwards

  auto cvt = [&](const float* s, US* dptr, size_t n) {
    int n4 = (int)(n / 4);
    k_cvt<<<dim3((n4 + 255) / 256), dim3(256), 0, stream>>>(s, dptr, n4);
  };
  cvt(x, xb, (size_t)Mr * 2048);
  cvt(w_down_q, wcat_down, (size_t)1536 * 2048);
  cvt(w_down_kv, wcat_down + (size_t)1536 * 2048, (size_t)512 * 2048);
  cvt(w_up_q, wcat_qup, (size_t)2048 * 1536);
  cvt(wq_r, wcat_qup + (size_t)2048 * 1536, (size_t)2048 * 1536);
  cvt(w_up_k, wcat_kvup, (size_t)2048 * 512);
  cvt(wk_r, wcat_kvup + (size_t)2048 * 512, (size_t)2048 * 512);
  cvt(w_up_v, wcat_kvup + (size_t)4096 * 512, (size_t)2048 * 512);
  cvt(wo, wob, (size_t)2048 * 2048);
  hipMemcpyAsync(bcat_down, b_down_q, 1536 * 4, hipMemcpyDeviceToDevice, stream);
  hipMemcpyAsync(bcat_down + 1536, b_down_kv, 512 * 4, hipMemcpyDeviceToDevice, stream);
  hipMemcpyAsync(bcat_qup, b_up_q, 2048 * 4, hipMemcpyDeviceToDevice, stream);
  hipMemcpyAsync(bcat_qup + 2048, bq_r, 2048 * 4, hipMemcpyDeviceToDevice, stream);
  hipMemcpyAsync(bcat_kvup, b_up_k, 2048 * 4, hipMemcpyDeviceToDevice, stream);
  hipMemcpyAsync(bcat_kvup + 2048, bk_r, 2048 * 4, hipMemcpyDeviceToDevice, stream);
  hipMemcpyAsync(bcat_kvup + 4096, b_up_v, 2048 * 4, hipMemcpyDeviceToDevice, stream);
  k_freqs<<<dim3((2048 * 1024 + 255) / 256), dim3(256), 0, stream>>>(cosT, sinT);

  auto gemm_bf = [&](const US* A, const US* B, const float* bias, US* C, int M, int N, int K,
                     int lda) {
    k_gemm_bt<false><<<dim3((N / 128) * (M / 128)), dim3(256), 0, stream>>>(A, B, bias, (void*)C,
                                                                            M, N, K, lda);
  };
  // fused down-projection: ct = x . [wdq; wdkv]^T   (512 blocks)
  gemm_bf(xb, wcat_down, bcat_down, ct, Mr, 2048, 2048, 2048);
  // fused q up-projection: t12 = ctq . [wuq; wqr]^T  (1024 blocks)
  gemm_bf(ct, wcat_qup, bcat_qup, t12, Mr, 4096, 1536, 2048);
  k_rope_combine<<<dim3((4096 * 1024 + 255) / 256), dim3(256), 0, stream>>>(t12, 4096, cosT, sinT,
                                                                            qb);
  // fused kv up-projection: kv3 = ctkv . [wuk; wkr; wuv]^T  (1536 blocks)
  gemm_bf(ct + 1536, wcat_kvup, bcat_kvup, kv3, Mr, 6144, 512, 2048);
  k_rope_combine<<<dim3((4096 * 1024 + 255) / 256), dim3(256), 0, stream>>>(kv3, 6144, cosT, sinT,
                                                                            kb);
  k_transpose_v<<<dim3(64, 128), dim3(256), 0, stream>>>(kv3 + 4096, 6144, vtb);
  // attention -> aout
  k_attn<<<dim3(16, 16, 2), dim3(256), 0, stream>>>(qb, kb, vtb, aout);
  // output projection (f32 out, 512 blocks)
  k_gemm_bt<true><<<dim3((2048 / 128) * (Mr / 128)), dim3(256), 0, stream>>>(aout, wob, bo, d_out,
                                                                             Mr, 2048, 2048, 2048);
}